// Round 1
// baseline (14175.337 us; speedup 1.0000x reference)
//
#include <hip/hip_runtime.h>
#include <hip/hip_bf16.h>

#define BB 32
#define TT 2048
#define MELS 80
#define HH 128
#define WW 64
#define DD 128

// ---------------- conv1d (SAME, K=5) ----------------
// block: (b, 64-wide t tile); 256 threads: t=tid&63, hg=tid>>6 (32 h each)
template<int CIN, bool RELU>
__global__ __launch_bounds__(256) void conv1d_k(const float* __restrict__ in,
                      const float* __restrict__ wt, const float* __restrict__ bias,
                      float* __restrict__ out) {
  __shared__ float s_in[CIN][68];
  const int bid = blockIdx.x;
  const int b = bid >> 5;          // /32 tiles
  const int t0 = (bid & 31) * 64;
  const int tid = threadIdx.x;
  for (int i = tid; i < CIN * 68; i += 256) {
    int c = i / 68, j = i - c * 68;
    int tt = t0 + j - 2;
    float v = 0.f;
    if (tt >= 0 && tt < TT) v = in[(b * CIN + c) * TT + tt];
    s_in[c][j] = v;
  }
  __syncthreads();
  const int t = tid & 63;
  const int hg = __builtin_amdgcn_readfirstlane(tid >> 6); // 0..3, wave-uniform
  float acc[32];
  #pragma unroll
  for (int i = 0; i < 32; ++i) acc[i] = bias[hg * 32 + i];
  for (int c = 0; c < CIN; ++c) {
    float x0 = s_in[c][t + 0], x1 = s_in[c][t + 1], x2 = s_in[c][t + 2],
          x3 = s_in[c][t + 3], x4 = s_in[c][t + 4];
    const float* wp = wt + (hg * 32) * CIN * 5 + c * 5;
    #pragma unroll
    for (int i = 0; i < 32; ++i) {
      const float* wr = wp + i * CIN * 5;
      acc[i] += wr[0] * x0 + wr[1] * x1 + wr[2] * x2 + wr[3] * x3 + wr[4] * x4;
    }
  }
  #pragma unroll
  for (int i = 0; i < 32; ++i) {
    float v = acc[i];
    if (RELU) v = fmaxf(v, 0.f);
    out[(b * HH + hg * 32 + i) * TT + t0 + t] = v;
  }
}

// ---------------- fused word-gather + conv2d #1 (relu) -> y1 (bf16) --------
// block: (b, w); 256 threads: d=tid&127, hg=tid>>7 (64 ho each)
__global__ __launch_bounds__(256) void conv2d1_k(const float* __restrict__ emb,
        const int* __restrict__ wb, const int* __restrict__ wlen,
        const float* __restrict__ cw, const float* __restrict__ cb,
        __hip_bfloat16* __restrict__ y1) {
  __shared__ float s_in[16][5][132];
  __shared__ int s_start[5], s_dur[5], s_val[5];
  const int bid = blockIdx.x;
  const int b = bid >> 6, w = bid & 63;
  const int tid = threadIdx.x;
  if (tid < 5) {
    int wq = w + tid - 2;
    int st = 0, du = 0, va = 0;
    if (wq >= 0 && wq < WW) {
      st = wb[b * 128 + wq];
      du = wb[b * 128 + 64 + wq] - st;
      va = (wq < wlen[b]) ? 1 : 0;
    }
    s_start[tid] = st; s_dur[tid] = du; s_val[tid] = va;
  }
  const int d = tid & 127;
  const int hg = __builtin_amdgcn_readfirstlane(tid >> 7);
  float acc[64];
  #pragma unroll
  for (int i = 0; i < 64; ++i) acc[i] = 0.f;

  for (int chunk = 0; chunk < 8; ++chunk) {
    __syncthreads();
    for (int i = tid; i < 16 * 5 * 132; i += 256) {
      int hi = i / 660; int r = i - hi * 660;
      int wi = r / 132; int j = r - wi * 132;
      int dq = j - 2;
      float v = 0.f;
      if (s_val[wi] && dq >= 0 && dq < 128 && dq < s_dur[wi]) {
        int idx = s_start[wi] + dq;      // guaranteed in [0,T)
        v = emb[(b * HH + chunk * 16 + hi) * TT + idx];
      }
      s_in[hi][wi][j] = v;
    }
    __syncthreads();
    for (int hi = 0; hi < 16; ++hi) {
      for (int kw = 0; kw < 5; ++kw) {
        float x0 = s_in[hi][kw][d + 0], x1 = s_in[hi][kw][d + 1],
              x2 = s_in[hi][kw][d + 2], x3 = s_in[hi][kw][d + 3],
              x4 = s_in[hi][kw][d + 4];
        const float* wp = cw + ((hg * 64) * HH + chunk * 16 + hi) * 25 + kw * 5;
        #pragma unroll
        for (int i = 0; i < 64; ++i) {
          const float* wr = wp + i * HH * 25;
          acc[i] += wr[0] * x0 + wr[1] * x1 + wr[2] * x2 + wr[3] * x3 + wr[4] * x4;
        }
      }
    }
  }
  #pragma unroll
  for (int i = 0; i < 64; ++i) {
    int ho = hg * 64 + i;
    float v = fmaxf(acc[i] + cb[ho], 0.f);
    y1[((b * HH + ho) * WW + w) * DD + d] = __float2bfloat16(v);
  }
}

// ---------------- conv2d #2 (relu) + einsum(lw) + relu -> z (f32) ----------
__global__ __launch_bounds__(256) void conv2d2_k(const __hip_bfloat16* __restrict__ y1,
        const float* __restrict__ cw, const float* __restrict__ cb,
        const float* __restrict__ lw, const float* __restrict__ lb,
        float* __restrict__ z) {
  __shared__ float s_in[16][5][132];
  __shared__ float s_part[4][64];
  const int bid = blockIdx.x;
  const int b = bid >> 6, w = bid & 63;
  const int tid = threadIdx.x;
  const int d = tid & 127;
  const int hg = __builtin_amdgcn_readfirstlane(tid >> 7);
  float acc[64];
  #pragma unroll
  for (int i = 0; i < 64; ++i) acc[i] = 0.f;

  for (int chunk = 0; chunk < 8; ++chunk) {
    __syncthreads();
    for (int i = tid; i < 16 * 5 * 132; i += 256) {
      int hi = i / 660; int r = i - hi * 660;
      int wi = r / 132; int j = r - wi * 132;
      int dq = j - 2;
      int wq = w + wi - 2;
      float v = 0.f;
      if (wq >= 0 && wq < WW && dq >= 0 && dq < DD)
        v = __bfloat162float(y1[((b * HH + chunk * 16 + hi) * WW + wq) * DD + dq]);
      s_in[hi][wi][j] = v;
    }
    __syncthreads();
    for (int hi = 0; hi < 16; ++hi) {
      for (int kw = 0; kw < 5; ++kw) {
        float x0 = s_in[hi][kw][d + 0], x1 = s_in[hi][kw][d + 1],
              x2 = s_in[hi][kw][d + 2], x3 = s_in[hi][kw][d + 3],
              x4 = s_in[hi][kw][d + 4];
        const float* wp = cw + ((hg * 64) * HH + chunk * 16 + hi) * 25 + kw * 5;
        #pragma unroll
        for (int i = 0; i < 64; ++i) {
          const float* wr = wp + i * HH * 25;
          acc[i] += wr[0] * x0 + wr[1] * x1 + wr[2] * x2 + wr[3] * x3 + wr[4] * x4;
        }
      }
    }
  }
  // epilogue: y2 = relu(acc+cb); partial z = sum_d y2*lw[d]
  const float lwv = lw[d];
  const int wave = __builtin_amdgcn_readfirstlane(tid >> 6);
  #pragma unroll
  for (int i = 0; i < 64; ++i) {
    float v = fmaxf(acc[i] + cb[hg * 64 + i], 0.f) * lwv;
    #pragma unroll
    for (int off = 32; off > 0; off >>= 1) v += __shfl_down(v, off, 64);
    if ((tid & 63) == 0) s_part[wave][i] = v;
  }
  __syncthreads();
  if (tid < 128) {
    int ho = tid;
    int g = ho >> 6, i = ho & 63;
    float zz = s_part[g * 2][i] + s_part[g * 2 + 1][i];
    zz = fmaxf(zz + lb[0], 0.f);
    z[(b * HH + ho) * WW + w] = zz;
  }
}

// ---------------- final conv2d (1 out channel, D=1 -> only kd=2) -----------
__global__ __launch_bounds__(64) void final_k(const float* __restrict__ z,
        const float* __restrict__ cw3, const float* __restrict__ cb3,
        float* __restrict__ out) {
  const int b = blockIdx.x;
  const int w = threadIdx.x; // 0..63
  float acc = cb3[0];
  for (int hi = 0; hi < HH; ++hi) {
    const float* zp = z + (b * HH + hi) * WW;
    #pragma unroll
    for (int kw = 0; kw < 5; ++kw) {
      int ww = w + kw - 2;
      if (ww >= 0 && ww < WW) acc += cw3[hi * 25 + kw * 5 + 2] * zp[ww];
    }
  }
  out[b * WW + w] = acc;
}

extern "C" void kernel_launch(void* const* d_in, const int* in_sizes, int n_in,
                              void* d_out, int out_size, void* d_ws, size_t ws_size,
                              hipStream_t stream) {
  const float* features = (const float*)d_in[0];
  const int*   wbnd     = (const int*)d_in[1];
  const int*   wlen     = (const int*)d_in[2];
  const float* w1  = (const float*)d_in[3];
  const float* b1  = (const float*)d_in[4];
  const float* w2  = (const float*)d_in[5];
  const float* b2  = (const float*)d_in[6];
  const float* w3  = (const float*)d_in[7];
  const float* b3  = (const float*)d_in[8];
  const float* cw1 = (const float*)d_in[9];
  const float* cb1 = (const float*)d_in[10];
  const float* cw2 = (const float*)d_in[11];
  const float* cb2 = (const float*)d_in[12];
  const float* lw  = (const float*)d_in[13];
  const float* lb  = (const float*)d_in[14];
  const float* cw3 = (const float*)d_in[15];
  const float* cb3 = (const float*)d_in[16];
  float* out = (float*)d_out;

  // workspace layout
  const size_t NX = (size_t)BB * HH * TT;      // 8,388,608
  float* x1 = (float*)d_ws;
  float* x2 = x1 + NX;
  __hip_bfloat16* y1 = (__hip_bfloat16*)(x2 + NX);
  float* z = (float*)(y1 + (size_t)BB * HH * WW * DD);

  conv1d_k<MELS, true><<<1024, 256, 0, stream>>>(features, w1, b1, x1);
  conv1d_k<HH,   true><<<1024, 256, 0, stream>>>(x1, w2, b2, x2);
  conv1d_k<HH,  false><<<1024, 256, 0, stream>>>(x2, w3, b3, x1); // emb -> x1
  conv2d1_k<<<BB * WW, 256, 0, stream>>>(x1, wbnd, wlen, cw1, cb1, y1);
  conv2d2_k<<<BB * WW, 256, 0, stream>>>(y1, cw2, cb2, lw, lb, z);
  final_k<<<BB, 64, 0, stream>>>(z, cw3, cb3, out);
}

// Round 2
// 2273.789 us; speedup vs baseline: 6.2342x; 6.2342x over previous
//
#include <hip/hip_runtime.h>
#include <hip/hip_bf16.h>

#define BB 32
#define TT 2048
#define MELS 80
#define HH 128
#define WW 64
#define DD 128

using bf16x8 = __attribute__((ext_vector_type(8))) short;
using f32x16 = __attribute__((ext_vector_type(16))) float;

// LDS patch X[d'=0..131][k=0..79] bf16, row stride 128 ushorts (256B),
// 16B-block XOR swizzle: blk' = blk ^ (row&7)  -> conflict-free b128 frag reads
__device__ __forceinline__ int xidx(int row, int k) {
  return row * 128 + ((((k >> 3) ^ row) & 7) << 3) + ((k >> 3) & 8) * 8 + (k & 7);
}
// note: ((k>>3) ^ (row&7)) keeps bit3 of blk only if we re-OR it; do it explicitly:
// blk' = (blk ^ (row&7))  with blk<16 toggles only low 3 bits -> bit3 preserved.
// (the helper above is equivalent: ((blk^row)&7) | (blk&8), then <<3)

// ---------------- conv1d (SAME, K=5) ----------------
template<int CIN, int RELU, int BF16OUT>
__global__ __launch_bounds__(256) void conv1d_k(const float* __restrict__ in,
                      const float* __restrict__ wt, const float* __restrict__ bias,
                      void* __restrict__ out_) {
  __shared__ float s_in[CIN][68];
  const int bid = blockIdx.x;
  const int b = bid >> 5;
  const int t0 = (bid & 31) * 64;
  const int tid = threadIdx.x;
  for (int i = tid; i < CIN * 68; i += 256) {
    int c = i / 68, j = i - c * 68;
    int tt = t0 + j - 2;
    float v = 0.f;
    if (tt >= 0 && tt < TT) v = in[(b * CIN + c) * TT + tt];
    s_in[c][j] = v;
  }
  __syncthreads();
  const int t = tid & 63;
  const int hg = __builtin_amdgcn_readfirstlane(tid >> 6);
  float acc[32];
  #pragma unroll
  for (int i = 0; i < 32; ++i) acc[i] = bias[hg * 32 + i];
  for (int c = 0; c < CIN; ++c) {
    float x0 = s_in[c][t + 0], x1 = s_in[c][t + 1], x2 = s_in[c][t + 2],
          x3 = s_in[c][t + 3], x4 = s_in[c][t + 4];
    const float* wp = wt + (hg * 32) * CIN * 5 + c * 5;
    #pragma unroll
    for (int i = 0; i < 32; ++i) {
      const float* wr = wp + i * CIN * 5;
      acc[i] += wr[0] * x0 + wr[1] * x1 + wr[2] * x2 + wr[3] * x3 + wr[4] * x4;
    }
  }
  #pragma unroll
  for (int i = 0; i < 32; ++i) {
    float v = acc[i];
    if (RELU) v = fmaxf(v, 0.f);
    size_t oi = (size_t)(b * HH + hg * 32 + i) * TT + t0 + t;
    if (BF16OUT) ((__hip_bfloat16*)out_)[oi] = __float2bfloat16(v);
    else         ((float*)out_)[oi] = v;
  }
}

// ---------------- weight repack: cw[ho][hi][kw][kd] f32 -> MFMA frag order bf16
// Wb layout (ushort): ((((kd*40 + s)*2 + half)*128 + m)*8 + e), k = s*16+half*8+e = hi*5+kw
__global__ __launch_bounds__(256) void repack_k(const float* __restrict__ cw,
                                                __hip_bfloat16* __restrict__ Wb) {
  int i = blockIdx.x * 256 + threadIdx.x;   // 5*40*2*128*8 = 409600 exact
  int e = i & 7;
  int m = (i >> 3) & 127;
  int h = (i >> 10) & 1;
  int rest = i >> 11;
  int s = rest % 40, kd = rest / 40;
  int k = s * 16 + h * 8 + e;
  int hi = k / 5, kw = k - hi * 5;
  float v = cw[((m * HH + hi) * 5 + kw) * 5 + kd];
  Wb[i] = __float2bfloat16(v);
}

// ---------------- fused gather + conv2d #1 (MFMA) -> y1 bf16 [B][H][W][D] ----
__global__ __launch_bounds__(256) void conv2d1_mfma(
    const ushort* __restrict__ emb, const int* __restrict__ wb,
    const int* __restrict__ wlen, const ushort* __restrict__ Wb,
    const float* __restrict__ cb, __hip_bfloat16* __restrict__ y1) {
  __shared__ __align__(16) ushort s_x[132 * 128];
  __shared__ int s_start[5], s_dur[5];
  const int bid = blockIdx.x;
  const int b = bid >> 6, w = bid & 63;
  const int tid = threadIdx.x;
  if (tid < 5) {
    int wq = w + tid - 2;
    int st = 0, du = 0;
    if (wq >= 0 && wq < WW && wq < wlen[b]) {
      st = wb[b * 128 + wq];
      du = min(wb[b * 128 + 64 + wq] - st, 128);
    }
    s_start[tid] = st; s_dur[tid] = du;
  }
  const int lane = tid & 63, wv = tid >> 6;
  const int l31 = lane & 31, half = lane >> 5;
  const int m_w = (wv >> 1) * 64, n_w = (wv & 1) * 64;
  f32x16 a00 = 0.f, a01 = 0.f, a10 = 0.f, a11 = 0.f;
  const bf16x8* Ap = (const bf16x8*)Wb;

  for (int chunk = 0; chunk < 8; ++chunk) {
    __syncthreads();
    // stage: X[dp][k] = gathered emb (bf16 bits), zeros outside word
    {
      const int kk0 = tid >> 7;        // 0/1
      const int dp = tid & 127;
      const int dq = dp - 2;
      for (int kk = 0; kk < 80; kk += 2) {
        int k = kk + kk0;
        int hi = k / 5, kw = k - hi * 5;
        ushort v = 0;
        if (dq >= 0 && dq < s_dur[kw])
          v = emb[(b * HH + chunk * 16 + hi) * TT + s_start[kw] + dq];
        s_x[xidx(dp, k)] = v;
      }
      for (int i = tid; i < 320; i += 256) { // tail dp 128..131
        int k = i >> 2, dp2 = 128 + (i & 3);
        int dq2 = dp2 - 2;
        int hi = k / 5, kw = k - hi * 5;
        ushort v = 0;
        if (dq2 < s_dur[kw])
          v = emb[(b * HH + chunk * 16 + hi) * TT + s_start[kw] + dq2];
        s_x[xidx(dp2, k)] = v;
      }
    }
    __syncthreads();
    #pragma unroll
    for (int ss = 0; ss < 5; ++ss) {
      #pragma unroll
      for (int kd = 0; kd < 5; ++kd) {
        int r0 = n_w + l31 + kd, r1 = r0 + 32;
        int blk = ss * 2 + half;
        bf16x8 bv0 = *(const bf16x8*)&s_x[r0 * 128 + ((blk ^ (r0 & 7)) << 3)];
        bf16x8 bv1 = *(const bf16x8*)&s_x[r1 * 128 + ((blk ^ (r1 & 7)) << 3)];
        int ai = ((kd * 40 + chunk * 5 + ss) * 2 + half) * 128 + m_w + l31;
        bf16x8 av0 = Ap[ai], av1 = Ap[ai + 32];
        a00 = __builtin_amdgcn_mfma_f32_32x32x16_bf16(av0, bv0, a00, 0, 0, 0);
        a01 = __builtin_amdgcn_mfma_f32_32x32x16_bf16(av0, bv1, a01, 0, 0, 0);
        a10 = __builtin_amdgcn_mfma_f32_32x32x16_bf16(av1, bv0, a10, 0, 0, 0);
        a11 = __builtin_amdgcn_mfma_f32_32x32x16_bf16(av1, bv1, a11, 0, 0, 0);
      }
    }
  }
  // epilogue: bias + relu, store bf16
  #pragma unroll
  for (int r = 0; r < 16; ++r) {
    int rowoff = (r & 3) + 8 * (r >> 2) + 4 * half;
    int ho0 = m_w + rowoff, ho1 = m_w + 32 + rowoff;
    float c0 = cb[ho0], c1 = cb[ho1];
    size_t o0 = ((size_t)(b * HH + ho0) * WW + w) * DD;
    size_t o1 = ((size_t)(b * HH + ho1) * WW + w) * DD;
    y1[o0 + n_w + l31]      = __float2bfloat16(fmaxf(a00[r] + c0, 0.f));
    y1[o0 + n_w + 32 + l31] = __float2bfloat16(fmaxf(a01[r] + c0, 0.f));
    y1[o1 + n_w + l31]      = __float2bfloat16(fmaxf(a10[r] + c1, 0.f));
    y1[o1 + n_w + 32 + l31] = __float2bfloat16(fmaxf(a11[r] + c1, 0.f));
  }
}

// ---------------- conv2d #2 (MFMA) + relu + einsum(lw) + relu -> z f32 ------
__global__ __launch_bounds__(256) void conv2d2_mfma(
    const ushort* __restrict__ y1, const ushort* __restrict__ Wb,
    const float* __restrict__ cb, const float* __restrict__ lw,
    const float* __restrict__ lb, float* __restrict__ z) {
  __shared__ __align__(16) ushort s_x[132 * 128];
  __shared__ float s_red[HH][2];
  const int bid = blockIdx.x;
  const int b = bid >> 6, w = bid & 63;
  const int tid = threadIdx.x;
  const int lane = tid & 63, wv = tid >> 6;
  const int l31 = lane & 31, half = lane >> 5;
  const int m_w = (wv >> 1) * 64, n_w = (wv & 1) * 64;
  f32x16 a00 = 0.f, a01 = 0.f, a10 = 0.f, a11 = 0.f;
  const bf16x8* Ap = (const bf16x8*)Wb;

  for (int chunk = 0; chunk < 8; ++chunk) {
    __syncthreads();
    {
      const int kk0 = tid >> 7;
      const int dp = tid & 127;
      const int dq = dp - 2;
      for (int kk = 0; kk < 80; kk += 2) {
        int k = kk + kk0;
        int hi = k / 5, kw = k - hi * 5;
        int wq = w + kw - 2;
        ushort v = 0;
        if (dq >= 0 && wq >= 0 && wq < WW)
          v = y1[((b * HH + chunk * 16 + hi) * WW + wq) * DD + dq];
        s_x[xidx(dp, k)] = v;
      }
      for (int i = tid; i < 320; i += 256) {
        int k = i >> 2, dp2 = 128 + (i & 3);
        int dq2 = dp2 - 2;
        int hi = k / 5, kw = k - hi * 5;
        int wq = w + kw - 2;
        ushort v = 0;
        if (dq2 < 128 && wq >= 0 && wq < WW)
          v = y1[((b * HH + chunk * 16 + hi) * WW + wq) * DD + dq2];
        s_x[xidx(dp2, k)] = v;
      }
    }
    __syncthreads();
    #pragma unroll
    for (int ss = 0; ss < 5; ++ss) {
      #pragma unroll
      for (int kd = 0; kd < 5; ++kd) {
        int r0 = n_w + l31 + kd, r1 = r0 + 32;
        int blk = ss * 2 + half;
        bf16x8 bv0 = *(const bf16x8*)&s_x[r0 * 128 + ((blk ^ (r0 & 7)) << 3)];
        bf16x8 bv1 = *(const bf16x8*)&s_x[r1 * 128 + ((blk ^ (r1 & 7)) << 3)];
        int ai = ((kd * 40 + chunk * 5 + ss) * 2 + half) * 128 + m_w + l31;
        bf16x8 av0 = Ap[ai], av1 = Ap[ai + 32];
        a00 = __builtin_amdgcn_mfma_f32_32x32x16_bf16(av0, bv0, a00, 0, 0, 0);
        a01 = __builtin_amdgcn_mfma_f32_32x32x16_bf16(av0, bv1, a01, 0, 0, 0);
        a10 = __builtin_amdgcn_mfma_f32_32x32x16_bf16(av1, bv0, a10, 0, 0, 0);
        a11 = __builtin_amdgcn_mfma_f32_32x32x16_bf16(av1, bv1, a11, 0, 0, 0);
      }
    }
  }
  // epilogue: relu(acc+cb)*lw, reduce over d (lanes of each 32-group), relu(+lb)
  const float lw0 = lw[n_w + l31], lw1 = lw[n_w + 32 + l31];
  #pragma unroll
  for (int r = 0; r < 16; ++r) {
    int rowoff = (r & 3) + 8 * (r >> 2) + 4 * half;
    {
      int ho = m_w + rowoff;
      float c = cb[ho];
      float v = fmaxf(a00[r] + c, 0.f) * lw0 + fmaxf(a01[r] + c, 0.f) * lw1;
      v += __shfl_xor(v, 1); v += __shfl_xor(v, 2); v += __shfl_xor(v, 4);
      v += __shfl_xor(v, 8); v += __shfl_xor(v, 16);
      if (l31 == 0) s_red[ho][wv & 1] = v;
    }
    {
      int ho = m_w + 32 + rowoff;
      float c = cb[ho];
      float v = fmaxf(a10[r] + c, 0.f) * lw0 + fmaxf(a11[r] + c, 0.f) * lw1;
      v += __shfl_xor(v, 1); v += __shfl_xor(v, 2); v += __shfl_xor(v, 4);
      v += __shfl_xor(v, 8); v += __shfl_xor(v, 16);
      if (l31 == 0) s_red[ho][wv & 1] = v;
    }
  }
  __syncthreads();
  if (tid < HH) {
    float zz = fmaxf(s_red[tid][0] + s_red[tid][1] + lb[0], 0.f);
    z[(b * HH + tid) * WW + w] = zz;
  }
}

// ---------------- final conv2d (1 out channel, D-dim=1 -> only kd=2) --------
__global__ __launch_bounds__(64) void final_k(const float* __restrict__ z,
        const float* __restrict__ cw3, const float* __restrict__ cb3,
        float* __restrict__ out) {
  const int b = blockIdx.x;
  const int w = threadIdx.x;
  float acc = cb3[0];
  for (int hi = 0; hi < HH; ++hi) {
    const float* zp = z + (b * HH + hi) * WW;
    #pragma unroll
    for (int kw = 0; kw < 5; ++kw) {
      int ww = w + kw - 2;
      if (ww >= 0 && ww < WW) acc += cw3[hi * 25 + kw * 5 + 2] * zp[ww];
    }
  }
  out[b * WW + w] = acc;
}

extern "C" void kernel_launch(void* const* d_in, const int* in_sizes, int n_in,
                              void* d_out, int out_size, void* d_ws, size_t ws_size,
                              hipStream_t stream) {
  const float* features = (const float*)d_in[0];
  const int*   wbnd     = (const int*)d_in[1];
  const int*   wlen     = (const int*)d_in[2];
  const float* w1  = (const float*)d_in[3];
  const float* b1  = (const float*)d_in[4];
  const float* w2  = (const float*)d_in[5];
  const float* b2  = (const float*)d_in[6];
  const float* w3  = (const float*)d_in[7];
  const float* b3  = (const float*)d_in[8];
  const float* cw1 = (const float*)d_in[9];
  const float* cb1 = (const float*)d_in[10];
  const float* cw2 = (const float*)d_in[11];
  const float* cb2 = (const float*)d_in[12];
  const float* lw  = (const float*)d_in[13];
  const float* lb  = (const float*)d_in[14];
  const float* cw3 = (const float*)d_in[15];
  const float* cb3 = (const float*)d_in[16];
  float* out = (float*)d_out;

  char* ws = (char*)d_ws;
  float* x1            = (float*)(ws + 0);                    // 33,554,432 B
  float* x2            = (float*)(ws + 33554432);             // 33,554,432 B
  __hip_bfloat16* emb  = (__hip_bfloat16*)(ws + 0);           // 16.8 MB (over x1)
  __hip_bfloat16* y1   = (__hip_bfloat16*)(ws + 33554432);    // 67 MB (over x2+)
  float* z             = (float*)(ws + 100663296);            // 1 MB
  __hip_bfloat16* Wb1  = (__hip_bfloat16*)(ws + 101711872);   // 819,200 B
  __hip_bfloat16* Wb2  = (__hip_bfloat16*)(ws + 102531072);   // 819,200 B

  repack_k<<<1600, 256, 0, stream>>>(cw1, Wb1);
  repack_k<<<1600, 256, 0, stream>>>(cw2, Wb2);
  conv1d_k<MELS, 1, 0><<<1024, 256, 0, stream>>>(features, w1, b1, x1);
  conv1d_k<HH,   1, 0><<<1024, 256, 0, stream>>>(x1, w2, b2, x2);
  conv1d_k<HH,   0, 1><<<1024, 256, 0, stream>>>(x2, w3, b3, emb);
  conv2d1_mfma<<<BB * WW, 256, 0, stream>>>((const ushort*)emb, wbnd, wlen,
                                            (const ushort*)Wb1, cb1, y1);
  conv2d2_mfma<<<BB * WW, 256, 0, stream>>>((const ushort*)y1, (const ushort*)Wb2,
                                            cb2, lw, lb, z);
  final_k<<<BB, 64, 0, stream>>>(z, cw3, cb3, out);
}

// Round 3
// 1137.857 us; speedup vs baseline: 12.4579x; 1.9983x over previous
//
#include <hip/hip_runtime.h>
#include <hip/hip_bf16.h>

#define BB 32
#define TT 2048
#define MELS 80
#define HH 128
#define WW 64
#define DD 128

using bf16x8 = __attribute__((ext_vector_type(8))) short;
using f32x16 = __attribute__((ext_vector_type(16))) float;
using u16x4  = __attribute__((ext_vector_type(4))) ushort;

#define MFMA(av, bv, acc) acc = __builtin_amdgcn_mfma_f32_32x32x16_bf16(av, bv, acc, 0, 0, 0)

__device__ __forceinline__ ushort bf16b(float f) {
  __hip_bfloat16 h = __float2bfloat16(f);
  return *(ushort*)&h;
}

// Epilogue helper: scatter one 32x32 C-tile into LDS s_y[col][row] (bf16,
// XOR-swizzled 16B blocks) with bias+optional relu.
__device__ __forceinline__ void dump_tile(const f32x16& a, int tl, int mb, int half,
                                          const float* __restrict__ bias, bool relu,
                                          ushort* s_y) {
  #pragma unroll
  for (int q = 0; q < 4; ++q) {
    int ho0 = mb + 8 * q + 4 * half;
    u16x4 p;
    #pragma unroll
    for (int j = 0; j < 4; ++j) {
      float v = a[q * 4 + j] + bias[ho0 + j];
      if (relu) v = fmaxf(v, 0.f);
      p[j] = bf16b(v);
    }
    *(u16x4*)&s_y[tl * 128 + (((ho0 >> 3) ^ (tl & 7)) << 3) + (ho0 & 7)] = p;
  }
}

// ---------------- features [b][80][t] f32 -> ft [b][t][128] bf16 (c>=80 -> 0)
__global__ __launch_bounds__(256) void tr_feat(const float* __restrict__ f,
                                               ushort* __restrict__ ft) {
  __shared__ float s[MELS][65];
  const int b = blockIdx.x >> 5, t0 = (blockIdx.x & 31) * 64;
  const int tid = threadIdx.x;
  for (int i = tid; i < MELS * 64; i += 256) {
    int c = i >> 6, t = i & 63;
    s[c][t] = f[(b * MELS + c) * TT + t0 + t];
  }
  __syncthreads();
  for (int i = tid; i < 64 * 128; i += 256) {
    int t = i >> 7, c = i & 127;
    float v = (c < MELS) ? s[c][t] : 0.f;
    ft[(b * TT + t0 + t) * 128 + c] = bf16b(v);
  }
}

// ---------------- weight repacks to MFMA A-frag order ----------------------
// conv1d: w[m=128][c=C][kw=5] -> Wb[kw][ss<NSS][half][m][e], c = ss*16+half*8+e
template<int NSS>
__global__ __launch_bounds__(256) void repack1d(const float* __restrict__ w,
                                                ushort* __restrict__ Wb) {
  int i = blockIdx.x * 256 + threadIdx.x;   // 5*NSS*2048 exact
  int e = i & 7, m = (i >> 3) & 127, half = (i >> 10) & 1;
  int r = i >> 11;
  int ss = r % NSS, kw = r / NSS;
  int c = ss * 16 + half * 8 + e;
  const int C = (NSS == 5) ? MELS : HH;
  Wb[i] = bf16b(w[(m * C + c) * 5 + kw]);
}
// conv2d: cw[m=128][hi=128][kw=5][kd=5] -> Wc[kd][kw][ss<8][half][m][e], hi = ss*16+half*8+e
__global__ __launch_bounds__(256) void repack2d(const float* __restrict__ cw,
                                                ushort* __restrict__ Wc) {
  int i = blockIdx.x * 256 + threadIdx.x;   // 409600 exact
  int e = i & 7, m = (i >> 3) & 127, half = (i >> 10) & 1, ss = (i >> 11) & 7;
  int r = i >> 14;
  int kw = r % 5, kd = r / 5;
  int hi = ss * 16 + half * 8 + e;
  Wc[i] = bf16b(cw[((m * HH + hi) * 5 + kw) * 5 + kd]);
}

// ---------------- conv1d via MFMA: xt[b][t][128] -> yt[b][t][128] ----------
// block: (b, 128-t tile); 4 waves 2x2; K = C*5 (k = kw*C + c)
template<int NSS, int RELU>
__global__ __launch_bounds__(256) void conv1d_mfma(
    const ushort* __restrict__ xt, const ushort* __restrict__ Wb,
    const float* __restrict__ bias, ushort* __restrict__ yt) {
  __shared__ __align__(16) ushort s_x[132 * 128];
  const int b = blockIdx.x >> 4;
  const int t0 = (blockIdx.x & 15) << 7;
  const int tid = threadIdx.x;
  const int lane = tid & 63, wv = tid >> 6;
  const int l31 = lane & 31, half = lane >> 5;
  const int m_w = (wv >> 1) * 64, n_w = (wv & 1) * 64;

  #pragma unroll
  for (int it = 0; it < 9; ++it) {
    int i = it * 256 + tid;
    if (i < 2112) {
      int row = i >> 4, blk = i & 15;
      int t = t0 + row - 2;
      bf16x8 v = (short)0;
      if (t >= 0 && t < TT) v = *(const bf16x8*)(xt + (b * TT + t) * 128 + blk * 8);
      *(bf16x8*)&s_x[row * 128 + ((blk ^ (row & 7)) << 3)] = v;
    }
  }
  __syncthreads();

  f32x16 a00 = 0.f, a01 = 0.f, a10 = 0.f, a11 = 0.f;
  const bf16x8* Ap = (const bf16x8*)Wb;
  #pragma unroll
  for (int kw = 0; kw < 5; ++kw) {
    #pragma unroll
    for (int ss = 0; ss < NSS; ++ss) {
      int r0 = n_w + l31 + kw, r1 = r0 + 32;
      int blk = ss * 2 + half;
      bf16x8 bv0 = *(const bf16x8*)&s_x[r0 * 128 + ((blk ^ (r0 & 7)) << 3)];
      bf16x8 bv1 = *(const bf16x8*)&s_x[r1 * 128 + ((blk ^ (r1 & 7)) << 3)];
      int ai = ((kw * NSS + ss) * 2 + half) * 128 + m_w + l31;
      bf16x8 av0 = Ap[ai], av1 = Ap[ai + 32];
      MFMA(av0, bv0, a00); MFMA(av0, bv1, a01);
      MFMA(av1, bv0, a10); MFMA(av1, bv1, a11);
    }
  }
  __syncthreads();
  dump_tile(a00, n_w + l31,      m_w,      half, bias, RELU != 0, s_x);
  dump_tile(a01, n_w + 32 + l31, m_w,      half, bias, RELU != 0, s_x);
  dump_tile(a10, n_w + l31,      m_w + 32, half, bias, RELU != 0, s_x);
  dump_tile(a11, n_w + 32 + l31, m_w + 32, half, bias, RELU != 0, s_x);
  __syncthreads();
  #pragma unroll
  for (int it = 0; it < 8; ++it) {
    int i = it * 256 + tid;           // 128*16 = 2048
    int tl = i >> 4, blk = i & 15;
    bf16x8 v = *(const bf16x8*)&s_x[tl * 128 + ((blk ^ (tl & 7)) << 3)];
    *(bf16x8*)(yt + (b * TT + t0 + tl) * 128 + blk * 8) = v;
  }
}

// ---------------- fused gather + conv2d #1 (MFMA) -> y1t[b][w][d][hi] ------
__global__ __launch_bounds__(256) void conv2d1_mfma(
    const ushort* __restrict__ embt, const int* __restrict__ wb,
    const int* __restrict__ wlen, const ushort* __restrict__ Wc,
    const float* __restrict__ cb, ushort* __restrict__ y1t) {
  __shared__ __align__(16) ushort s_x[132 * 128];
  __shared__ int s_start[5], s_dur[5];
  const int bid = blockIdx.x;
  const int b = bid >> 6, w = bid & 63;
  const int tid = threadIdx.x;
  if (tid < 5) {
    int wq = w + tid - 2;
    int st = 0, du = 0;
    if (wq >= 0 && wq < WW && wq < wlen[b]) {
      st = wb[b * 128 + wq];
      du = min(wb[b * 128 + 64 + wq] - st, 128);
    }
    s_start[tid] = st; s_dur[tid] = du;
  }
  const int lane = tid & 63, wv = tid >> 6;
  const int l31 = lane & 31, half = lane >> 5;
  const int m_w = (wv >> 1) * 64, n_w = (wv & 1) * 64;
  f32x16 a00 = 0.f, a01 = 0.f, a10 = 0.f, a11 = 0.f;
  const bf16x8* Ap = (const bf16x8*)Wc;

  for (int kw = 0; kw < 5; ++kw) {
    __syncthreads();
    const int st = s_start[kw], du = s_dur[kw];
    #pragma unroll
    for (int it = 0; it < 9; ++it) {
      int i = it * 256 + tid;
      if (i < 2112) {
        int row = i >> 4, blk = i & 15;
        int dq = row - 2;
        bf16x8 v = (short)0;
        if (dq >= 0 && dq < du)
          v = *(const bf16x8*)(embt + (b * TT + st + dq) * 128 + blk * 8);
        *(bf16x8*)&s_x[row * 128 + ((blk ^ (row & 7)) << 3)] = v;
      }
    }
    __syncthreads();
    #pragma unroll
    for (int ss = 0; ss < 8; ++ss) {
      #pragma unroll
      for (int kd = 0; kd < 5; ++kd) {
        int r0 = n_w + l31 + kd, r1 = r0 + 32;
        int blk = ss * 2 + half;
        bf16x8 bv0 = *(const bf16x8*)&s_x[r0 * 128 + ((blk ^ (r0 & 7)) << 3)];
        bf16x8 bv1 = *(const bf16x8*)&s_x[r1 * 128 + ((blk ^ (r1 & 7)) << 3)];
        int ai = (((kd * 5 + kw) * 8 + ss) * 2 + half) * 128 + m_w + l31;
        bf16x8 av0 = Ap[ai], av1 = Ap[ai + 32];
        MFMA(av0, bv0, a00); MFMA(av0, bv1, a01);
        MFMA(av1, bv0, a10); MFMA(av1, bv1, a11);
      }
    }
  }
  __syncthreads();
  dump_tile(a00, n_w + l31,      m_w,      half, cb, true, s_x);
  dump_tile(a01, n_w + 32 + l31, m_w,      half, cb, true, s_x);
  dump_tile(a10, n_w + l31,      m_w + 32, half, cb, true, s_x);
  dump_tile(a11, n_w + 32 + l31, m_w + 32, half, cb, true, s_x);
  __syncthreads();
  #pragma unroll
  for (int it = 0; it < 8; ++it) {
    int i = it * 256 + tid;           // d-major tile, fully contiguous 32KB
    int d = i >> 4, blk = i & 15;
    bf16x8 v = *(const bf16x8*)&s_x[d * 128 + ((blk ^ (d & 7)) << 3)];
    *(bf16x8*)(y1t + ((b * WW + w) * DD + d) * 128 + blk * 8) = v;
  }
}

// ---------------- conv2d #2 (MFMA) + relu + einsum(lw) + relu -> z f32 -----
__global__ __launch_bounds__(256) void conv2d2_mfma(
    const ushort* __restrict__ y1t, const ushort* __restrict__ Wc,
    const float* __restrict__ cb, const float* __restrict__ lw,
    const float* __restrict__ lb, float* __restrict__ z) {
  __shared__ __align__(16) ushort s_x[132 * 128];
  const int bid = blockIdx.x;
  const int b = bid >> 6, w = bid & 63;
  const int tid = threadIdx.x;
  const int lane = tid & 63, wv = tid >> 6;
  const int l31 = lane & 31, half = lane >> 5;
  const int m_w = (wv >> 1) * 64, n_w = (wv & 1) * 64;
  f32x16 a00 = 0.f, a01 = 0.f, a10 = 0.f, a11 = 0.f;
  const bf16x8* Ap = (const bf16x8*)Wc;

  for (int kw = 0; kw < 5; ++kw) {
    __syncthreads();
    const int wq = w + kw - 2;
    const int wok = (wq >= 0 && wq < WW);
    #pragma unroll
    for (int it = 0; it < 9; ++it) {
      int i = it * 256 + tid;
      if (i < 2112) {
        int row = i >> 4, blk = i & 15;
        int dq = row - 2;
        bf16x8 v = (short)0;
        if (wok && dq >= 0 && dq < DD)
          v = *(const bf16x8*)(y1t + ((b * WW + wq) * DD + dq) * 128 + blk * 8);
        *(bf16x8*)&s_x[row * 128 + ((blk ^ (row & 7)) << 3)] = v;
      }
    }
    __syncthreads();
    #pragma unroll
    for (int ss = 0; ss < 8; ++ss) {
      #pragma unroll
      for (int kd = 0; kd < 5; ++kd) {
        int r0 = n_w + l31 + kd, r1 = r0 + 32;
        int blk = ss * 2 + half;
        bf16x8 bv0 = *(const bf16x8*)&s_x[r0 * 128 + ((blk ^ (r0 & 7)) << 3)];
        bf16x8 bv1 = *(const bf16x8*)&s_x[r1 * 128 + ((blk ^ (r1 & 7)) << 3)];
        int ai = (((kd * 5 + kw) * 8 + ss) * 2 + half) * 128 + m_w + l31;
        bf16x8 av0 = Ap[ai], av1 = Ap[ai + 32];
        MFMA(av0, bv0, a00); MFMA(av0, bv1, a01);
        MFMA(av1, bv0, a10); MFMA(av1, bv1, a11);
      }
    }
  }
  // epilogue: relu(acc+cb)*lw, reduce over d, relu(+lb)
  __syncthreads();
  float* s_red = (float*)s_x;           // [128][2]
  const float lw0 = lw[n_w + l31], lw1 = lw[n_w + 32 + l31];
  #pragma unroll
  for (int r = 0; r < 16; ++r) {
    int rowoff = (r & 3) + 8 * (r >> 2) + 4 * half;
    {
      int ho = m_w + rowoff;
      float c = cb[ho];
      float v = fmaxf(a00[r] + c, 0.f) * lw0 + fmaxf(a01[r] + c, 0.f) * lw1;
      v += __shfl_xor(v, 1); v += __shfl_xor(v, 2); v += __shfl_xor(v, 4);
      v += __shfl_xor(v, 8); v += __shfl_xor(v, 16);
      if (l31 == 0) s_red[ho * 2 + (wv & 1)] = v;
    }
    {
      int ho = m_w + 32 + rowoff;
      float c = cb[ho];
      float v = fmaxf(a10[r] + c, 0.f) * lw0 + fmaxf(a11[r] + c, 0.f) * lw1;
      v += __shfl_xor(v, 1); v += __shfl_xor(v, 2); v += __shfl_xor(v, 4);
      v += __shfl_xor(v, 8); v += __shfl_xor(v, 16);
      if (l31 == 0) s_red[ho * 2 + (wv & 1)] = v;
    }
  }
  __syncthreads();
  if (tid < HH) {
    float zz = fmaxf(s_red[tid * 2] + s_red[tid * 2 + 1] + lb[0], 0.f);
    z[(b * HH + tid) * WW + w] = zz;
  }
}

// ---------------- final conv2d (1 out channel, D-dim=1 -> only kd=2) -------
__global__ __launch_bounds__(64) void final_k(const float* __restrict__ z,
        const float* __restrict__ cw3, const float* __restrict__ cb3,
        float* __restrict__ out) {
  const int b = blockIdx.x;
  const int w = threadIdx.x;
  float acc = cb3[0];
  for (int hi = 0; hi < HH; ++hi) {
    const float* zp = z + (b * HH + hi) * WW;
    #pragma unroll
    for (int kw = 0; kw < 5; ++kw) {
      int ww = w + kw - 2;
      if (ww >= 0 && ww < WW) acc += cw3[hi * 25 + kw * 5 + 2] * zp[ww];
    }
  }
  out[b * WW + w] = acc;
}

extern "C" void kernel_launch(void* const* d_in, const int* in_sizes, int n_in,
                              void* d_out, int out_size, void* d_ws, size_t ws_size,
                              hipStream_t stream) {
  const float* features = (const float*)d_in[0];
  const int*   wbnd     = (const int*)d_in[1];
  const int*   wlen     = (const int*)d_in[2];
  const float* w1  = (const float*)d_in[3];
  const float* b1  = (const float*)d_in[4];
  const float* w2  = (const float*)d_in[5];
  const float* b2  = (const float*)d_in[6];
  const float* w3  = (const float*)d_in[7];
  const float* b3  = (const float*)d_in[8];
  const float* cw1 = (const float*)d_in[9];
  const float* cb1 = (const float*)d_in[10];
  const float* cw2 = (const float*)d_in[11];
  const float* cb2 = (const float*)d_in[12];
  const float* lw  = (const float*)d_in[13];
  const float* lb  = (const float*)d_in[14];
  const float* cw3 = (const float*)d_in[15];
  const float* cb3 = (const float*)d_in[16];
  float* out = (float*)d_out;

  char* ws = (char*)d_ws;
  ushort* ft   = (ushort*)(ws + 0);           // 16,777,216 B  [b][t][128]
  ushort* x1t  = (ushort*)(ws + 16777216);    // 16,777,216 B
  ushort* x2t  = (ushort*)(ws + 33554432);    // 16,777,216 B
  ushort* embt = (ushort*)(ws + 0);           // over ft (dead after layer1)
  ushort* y1t  = (ushort*)(ws + 16777216);    // 67,108,864 B (over x1t/x2t, dead)
  float*  z    = (float*)(ws + 83886080);     // 1,048,576 B
  ushort* Wb1  = (ushort*)(ws + 84934656);    // 102,400 B
  ushort* Wb2  = (ushort*)(ws + 85037056);    // 163,840 B
  ushort* Wb3  = (ushort*)(ws + 85200896);    // 163,840 B
  ushort* Wc1  = (ushort*)(ws + 85364736);    // 819,200 B
  ushort* Wc2  = (ushort*)(ws + 86183936);    // 819,200 B

  tr_feat<<<1024, 256, 0, stream>>>(features, ft);
  repack1d<5><<<200, 256, 0, stream>>>(w1, Wb1);
  repack1d<8><<<320, 256, 0, stream>>>(w2, Wb2);
  repack1d<8><<<320, 256, 0, stream>>>(w3, Wb3);
  repack2d<<<1600, 256, 0, stream>>>(cw1, Wc1);
  repack2d<<<1600, 256, 0, stream>>>(cw2, Wc2);
  conv1d_mfma<5, 1><<<512, 256, 0, stream>>>(ft, Wb1, b1, x1t);
  conv1d_mfma<8, 1><<<512, 256, 0, stream>>>(x1t, Wb2, b2, x2t);
  conv1d_mfma<8, 0><<<512, 256, 0, stream>>>(x2t, Wb3, b3, embt);
  conv2d1_mfma<<<BB * WW, 256, 0, stream>>>(embt, wbnd, wlen, Wc1, cb1, y1t);
  conv2d2_mfma<<<BB * WW, 256, 0, stream>>>(y1t, Wc2, cb2, lw, lb, z);
  final_k<<<BB, 64, 0, stream>>>(z, cw3, cb3, out);
}

// Round 4
// 592.517 us; speedup vs baseline: 23.9239x; 1.9204x over previous
//
#include <hip/hip_runtime.h>
#include <hip/hip_bf16.h>

#define BB 32
#define TT 2048
#define MELS 80
#define HH 128
#define WW 64
#define DD 128

using bf16x8 = __attribute__((ext_vector_type(8))) short;
using f32x16 = __attribute__((ext_vector_type(16))) float;
using u16x4  = __attribute__((ext_vector_type(4))) ushort;

#define MFMA(av, bv, acc) acc = __builtin_amdgcn_mfma_f32_32x32x16_bf16(av, bv, acc, 0, 0, 0)

__device__ __forceinline__ ushort bf16b(float f) {
  __hip_bfloat16 h = __float2bfloat16(f);
  return *(ushort*)&h;
}

// async global->LDS 16B DMA (linear LDS dest; swizzle goes on the SOURCE)
__device__ __forceinline__ void g2l16(const ushort* g, ushort* l) {
  __builtin_amdgcn_global_load_lds((const __attribute__((address_space(1))) void*)g,
                                   (__attribute__((address_space(3))) void*)l, 16, 0, 0);
}

// Epilogue helper: scatter one 32x32 C-tile into LDS s_y[col][row] (bf16,
// 4-bit XOR swizzle on 16B blocks) with bias+optional relu.
__device__ __forceinline__ void dump_tile(const f32x16& a, int tl, int mb, int half,
                                          const float* __restrict__ bias, bool relu,
                                          ushort* s_y) {
  #pragma unroll
  for (int q = 0; q < 4; ++q) {
    int ho0 = mb + 8 * q + 4 * half;
    u16x4 p;
    #pragma unroll
    for (int j = 0; j < 4; ++j) {
      float v = a[q * 4 + j] + bias[ho0 + j];
      if (relu) v = fmaxf(v, 0.f);
      p[j] = bf16b(v);
    }
    *(u16x4*)&s_y[tl * 128 + (((ho0 >> 3) ^ (tl & 15)) << 3) + (ho0 & 7)] = p;
  }
}

// ---------------- features [b][80][t] f32 -> ft [b][t][128] bf16 (c>=80 -> 0)
__global__ __launch_bounds__(256) void tr_feat(const float* __restrict__ f,
                                               ushort* __restrict__ ft) {
  __shared__ float s[MELS][65];
  const int b = blockIdx.x >> 5, t0 = (blockIdx.x & 31) * 64;
  const int tid = threadIdx.x;
  for (int i = tid; i < MELS * 64; i += 256) {
    int c = i >> 6, t = i & 63;
    s[c][t] = f[(b * MELS + c) * TT + t0 + t];
  }
  __syncthreads();
  for (int i = tid; i < 64 * 128; i += 256) {
    int t = i >> 7, c = i & 127;
    float v = (c < MELS) ? s[c][t] : 0.f;
    ft[(b * TT + t0 + t) * 128 + c] = bf16b(v);
  }
}

// ---------------- weight repacks to MFMA A-frag order ----------------------
template<int NSS>
__global__ __launch_bounds__(256) void repack1d(const float* __restrict__ w,
                                                ushort* __restrict__ Wb) {
  int i = blockIdx.x * 256 + threadIdx.x;   // 5*NSS*2048 exact
  int e = i & 7, m = (i >> 3) & 127, half = (i >> 10) & 1;
  int r = i >> 11;
  int ss = r % NSS, kw = r / NSS;
  int c = ss * 16 + half * 8 + e;
  const int C = (NSS == 5) ? MELS : HH;
  Wb[i] = bf16b(w[(m * C + c) * 5 + kw]);
}
__global__ __launch_bounds__(256) void repack2d(const float* __restrict__ cw,
                                                ushort* __restrict__ Wc) {
  int i = blockIdx.x * 256 + threadIdx.x;   // 409600 exact
  int e = i & 7, m = (i >> 3) & 127, half = (i >> 10) & 1, ss = (i >> 11) & 7;
  int r = i >> 14;
  int kw = r % 5, kd = r / 5;
  int hi = ss * 16 + half * 8 + e;
  Wc[i] = bf16b(cw[((m * HH + hi) * 5 + kw) * 5 + kd]);
}

// ---------------- conv1d via MFMA: xt[b][t][128] -> yt[b][t][128] ----------
template<int NSS, int RELU>
__global__ __launch_bounds__(256) void conv1d_mfma(
    const ushort* __restrict__ xt, const ushort* __restrict__ Wb,
    const float* __restrict__ bias, ushort* __restrict__ yt,
    const ushort* __restrict__ zp) {
  __shared__ __align__(16) ushort s_x[2112 * 8];
  const int bid = blockIdx.x;
  const int nid = (bid & 7) * 64 + (bid >> 3);   // XCD-chunked (512 % 8 == 0)
  const int b = nid >> 4;
  const int t0 = (nid & 15) << 7;
  const int tid = threadIdx.x;
  const int lane = tid & 63, wv = tid >> 6;
  const int l31 = lane & 31, half = lane >> 5;
  const int m_w = (wv >> 1) * 64, n_w = (wv & 1) * 64;

  #pragma unroll
  for (int it = 0; it < 9; ++it) {
    int slot = it * 256 + tid;
    if (slot < 2112) {
      int row = slot >> 4, bsw = (slot & 15) ^ (row & 15);
      int t = t0 + row - 2;
      const ushort* src = (t >= 0 && t < TT)
          ? xt + (((size_t)(b * TT + t)) << 7) + bsw * 8 : zp;
      g2l16(src, s_x + slot * 8);
    }
  }
  __syncthreads();

  f32x16 a00 = 0.f, a01 = 0.f, a10 = 0.f, a11 = 0.f;
  const bf16x8* Ap = (const bf16x8*)Wb;
  constexpr int G = 5 * NSS;
  bf16x8 ar[3][2];
  #pragma unroll
  for (int p = 0; p < 2; ++p) {
    ar[p][0] = Ap[(p * 2 + half) * 128 + m_w + l31];
    ar[p][1] = Ap[(p * 2 + half) * 128 + m_w + l31 + 32];
  }
  #pragma unroll
  for (int g = 0; g < G; ++g) {
    if (g + 2 < G) {
      ar[(g + 2) % 3][0] = Ap[((g + 2) * 2 + half) * 128 + m_w + l31];
      ar[(g + 2) % 3][1] = Ap[((g + 2) * 2 + half) * 128 + m_w + l31 + 32];
    }
    const int kw = g / NSS, ss = g % NSS;
    int r0 = n_w + l31 + kw, r1 = r0 + 32;
    int blk = ss * 2 + half;
    bf16x8 bv0 = *(const bf16x8*)&s_x[r0 * 128 + ((blk ^ (r0 & 15)) << 3)];
    bf16x8 bv1 = *(const bf16x8*)&s_x[r1 * 128 + ((blk ^ (r1 & 15)) << 3)];
    bf16x8 av0 = ar[g % 3][0], av1 = ar[g % 3][1];
    MFMA(av0, bv0, a00); MFMA(av0, bv1, a01);
    MFMA(av1, bv0, a10); MFMA(av1, bv1, a11);
  }
  __syncthreads();
  dump_tile(a00, n_w + l31,      m_w,      half, bias, RELU != 0, s_x);
  dump_tile(a01, n_w + 32 + l31, m_w,      half, bias, RELU != 0, s_x);
  dump_tile(a10, n_w + l31,      m_w + 32, half, bias, RELU != 0, s_x);
  dump_tile(a11, n_w + 32 + l31, m_w + 32, half, bias, RELU != 0, s_x);
  __syncthreads();
  #pragma unroll
  for (int it = 0; it < 8; ++it) {
    int i = it * 256 + tid;
    int tl = i >> 4, blk = i & 15;
    bf16x8 v = *(const bf16x8*)&s_x[tl * 128 + ((blk ^ (tl & 15)) << 3)];
    *(bf16x8*)(yt + (((size_t)(b * TT + t0 + tl)) << 7) + blk * 8) = v;
  }
}

// ---- shared compute macro for conv2d: one kw slab, A-regs double-buffered --
#define COMPUTE2D(KW, BUF)                                                     \
  {                                                                            \
    bf16x8 ar[2][8];                                                           \
    _Pragma("unroll")                                                          \
    for (int j = 0; j < 8; ++j)                                                \
      ar[0][j] = Ap[(((0 * 5 + (KW)) * 8 + (j >> 1)) * 2 + half) * 128 +       \
                    m_w + l31 + (j & 1) * 32];                                 \
    _Pragma("unroll")                                                          \
    for (int g = 0; g < 10; ++g) {                                             \
      int kd = g >> 1, sh = (g & 1) * 4;                                       \
      if (g < 9) {                                                             \
        int kd2 = (g + 1) >> 1, sh2 = ((g + 1) & 1) * 4;                       \
        _Pragma("unroll")                                                      \
        for (int j = 0; j < 8; ++j)                                            \
          ar[(g + 1) & 1][j] = Ap[(((kd2 * 5 + (KW)) * 8 + sh2 + (j >> 1)) * 2 \
                                   + half) * 128 + m_w + l31 + (j & 1) * 32];  \
      }                                                                        \
      _Pragma("unroll")                                                        \
      for (int s2 = 0; s2 < 4; ++s2) {                                         \
        int ss = sh + s2;                                                      \
        int r0 = n_w + l31 + kd, r1 = r0 + 32;                                 \
        int blk = ss * 2 + half;                                               \
        bf16x8 bv0 = *(const bf16x8*)&(BUF)[r0 * 128 + ((blk ^ (r0 & 15)) << 3)]; \
        bf16x8 bv1 = *(const bf16x8*)&(BUF)[r1 * 128 + ((blk ^ (r1 & 15)) << 3)]; \
        MFMA(ar[g & 1][s2 * 2], bv0, a00);                                     \
        MFMA(ar[g & 1][s2 * 2], bv1, a01);                                     \
        MFMA(ar[g & 1][s2 * 2 + 1], bv0, a10);                                 \
        MFMA(ar[g & 1][s2 * 2 + 1], bv1, a11);                                 \
      }                                                                        \
    }                                                                          \
  }

// ---------------- fused gather + conv2d #1 (MFMA) -> y1t[b][w][d][hi] ------
__global__ __launch_bounds__(256) void conv2d1_mfma(
    const ushort* __restrict__ embt, const int* __restrict__ wb,
    const int* __restrict__ wlen, const ushort* __restrict__ Wc,
    const float* __restrict__ cb, ushort* __restrict__ y1t,
    const ushort* __restrict__ zp) {
  extern __shared__ __align__(16) ushort smem[];   // 2 x 16896 ushorts
  const int bid = blockIdx.x;
  const int nid = (bid & 7) * 256 + (bid >> 3);    // XCD-chunked (2048 % 8 == 0)
  const int b = nid >> 6, w = nid & 63;
  const int tid = threadIdx.x;
  const int lane = tid & 63, wv = tid >> 6;
  const int l31 = lane & 31, half = lane >> 5;
  const int m_w = (wv >> 1) * 64, n_w = (wv & 1) * 64;

  int stv[5], duv[5];
  const int wl = wlen[b];
  #pragma unroll
  for (int i = 0; i < 5; ++i) {
    int wq = w + i - 2;
    bool ok = ((unsigned)wq < WW) && (wq < wl);
    int st = ok ? wb[b * 128 + wq] : 0;
    int en = ok ? wb[b * 128 + 64 + wq] : 0;
    stv[i] = st;
    duv[i] = ok ? min(en - st, 128) : 0;
  }

#define STAGE1(KW, BUF)                                                        \
  {                                                                            \
    const int st_ = stv[KW], du_ = duv[KW];                                    \
    _Pragma("unroll")                                                          \
    for (int it = 0; it < 9; ++it) {                                           \
      int slot = it * 256 + tid;                                               \
      if (slot < 2112) {                                                       \
        int row = slot >> 4, bsw = (slot & 15) ^ (row & 15);                   \
        int dq = row - 2;                                                      \
        const ushort* src = ((unsigned)dq < (unsigned)du_)                     \
            ? embt + (((size_t)(b * TT + st_ + dq)) << 7) + bsw * 8 : zp;      \
        g2l16(src, (BUF) + slot * 8);                                          \
      }                                                                        \
    }                                                                          \
  }

  STAGE1(0, smem);
  __syncthreads();

  f32x16 a00 = 0.f, a01 = 0.f, a10 = 0.f, a11 = 0.f;
  const bf16x8* Ap = (const bf16x8*)Wc;

  #pragma unroll
  for (int kw = 0; kw < 5; ++kw) {
    ushort* cur = smem + (kw & 1) * 16896;
    if (kw < 4) {
      ushort* nxt = smem + ((kw + 1) & 1) * 16896;
      switch (kw + 1) {     // compile-time under unroll
        case 1: STAGE1(1, nxt); break;
        case 2: STAGE1(2, nxt); break;
        case 3: STAGE1(3, nxt); break;
        case 4: STAGE1(4, nxt); break;
      }
    }
    COMPUTE2D(kw, cur);
    __syncthreads();
  }
#undef STAGE1

  dump_tile(a00, n_w + l31,      m_w,      half, cb, true, smem);
  dump_tile(a01, n_w + 32 + l31, m_w,      half, cb, true, smem);
  dump_tile(a10, n_w + l31,      m_w + 32, half, cb, true, smem);
  dump_tile(a11, n_w + 32 + l31, m_w + 32, half, cb, true, smem);
  __syncthreads();
  #pragma unroll
  for (int it = 0; it < 8; ++it) {
    int i = it * 256 + tid;
    int d = i >> 4, blk = i & 15;
    bf16x8 v = *(const bf16x8*)&smem[d * 128 + ((blk ^ (d & 15)) << 3)];
    *(bf16x8*)(y1t + (((size_t)(b * WW + w) * DD + d) << 7) + blk * 8) = v;
  }
}

// ---------------- conv2d #2 (MFMA) + relu + einsum(lw) + relu -> z f32 -----
__global__ __launch_bounds__(256) void conv2d2_mfma(
    const ushort* __restrict__ y1t, const ushort* __restrict__ Wc,
    const float* __restrict__ cb, const float* __restrict__ lw,
    const float* __restrict__ lb, float* __restrict__ z,
    const ushort* __restrict__ zp) {
  extern __shared__ __align__(16) ushort smem[];   // 2 x 16896 ushorts
  const int bid = blockIdx.x;
  const int nid = (bid & 7) * 256 + (bid >> 3);
  const int b = nid >> 6, w = nid & 63;
  const int tid = threadIdx.x;
  const int lane = tid & 63, wv = tid >> 6;
  const int l31 = lane & 31, half = lane >> 5;
  const int m_w = (wv >> 1) * 64, n_w = (wv & 1) * 64;

#define STAGE2(KW, BUF)                                                        \
  {                                                                            \
    const int wq_ = w + (KW) - 2;                                              \
    const bool wok_ = (unsigned)wq_ < WW;                                      \
    _Pragma("unroll")                                                          \
    for (int it = 0; it < 9; ++it) {                                           \
      int slot = it * 256 + tid;                                               \
      if (slot < 2112) {                                                       \
        int row = slot >> 4, bsw = (slot & 15) ^ (row & 15);                   \
        int dq = row - 2;                                                      \
        const ushort* src = (wok_ && (unsigned)dq < (unsigned)DD)              \
            ? y1t + (((size_t)(b * WW + wq_) * DD + dq) << 7) + bsw * 8 : zp;  \
        g2l16(src, (BUF) + slot * 8);                                          \
      }                                                                        \
    }                                                                          \
  }

  STAGE2(0, smem);
  __syncthreads();

  f32x16 a00 = 0.f, a01 = 0.f, a10 = 0.f, a11 = 0.f;
  const bf16x8* Ap = (const bf16x8*)Wc;

  #pragma unroll
  for (int kw = 0; kw < 5; ++kw) {
    ushort* cur = smem + (kw & 1) * 16896;
    if (kw < 4) {
      ushort* nxt = smem + ((kw + 1) & 1) * 16896;
      switch (kw + 1) {
        case 1: STAGE2(1, nxt); break;
        case 2: STAGE2(2, nxt); break;
        case 3: STAGE2(3, nxt); break;
        case 4: STAGE2(4, nxt); break;
      }
    }
    COMPUTE2D(kw, cur);
    __syncthreads();
  }
#undef STAGE2

  // epilogue: relu(acc+cb)*lw, reduce over d, relu(+lb)
  float* s_red = (float*)smem;            // [128][2]
  const float lw0 = lw[n_w + l31], lw1 = lw[n_w + 32 + l31];
  #pragma unroll
  for (int r = 0; r < 16; ++r) {
    int rowoff = (r & 3) + 8 * (r >> 2) + 4 * half;
    {
      int ho = m_w + rowoff;
      float c = cb[ho];
      float v = fmaxf(a00[r] + c, 0.f) * lw0 + fmaxf(a01[r] + c, 0.f) * lw1;
      v += __shfl_xor(v, 1); v += __shfl_xor(v, 2); v += __shfl_xor(v, 4);
      v += __shfl_xor(v, 8); v += __shfl_xor(v, 16);
      if (l31 == 0) s_red[ho * 2 + (wv & 1)] = v;
    }
    {
      int ho = m_w + 32 + rowoff;
      float c = cb[ho];
      float v = fmaxf(a10[r] + c, 0.f) * lw0 + fmaxf(a11[r] + c, 0.f) * lw1;
      v += __shfl_xor(v, 1); v += __shfl_xor(v, 2); v += __shfl_xor(v, 4);
      v += __shfl_xor(v, 8); v += __shfl_xor(v, 16);
      if (l31 == 0) s_red[ho * 2 + (wv & 1)] = v;
    }
  }
  __syncthreads();
  if (tid < HH) {
    float zz = fmaxf(s_red[tid * 2] + s_red[tid * 2 + 1] + lb[0], 0.f);
    z[(b * HH + tid) * WW + w] = zz;
  }
}

// ---------------- final conv2d (1 out channel, D-dim=1 -> only kd=2) -------
__global__ __launch_bounds__(64) void final_k(const float* __restrict__ z,
        const float* __restrict__ cw3, const float* __restrict__ cb3,
        float* __restrict__ out) {
  const int b = blockIdx.x;
  const int w = threadIdx.x;
  float acc = cb3[0];
  for (int hi = 0; hi < HH; ++hi) {
    const float* zp = z + (b * HH + hi) * WW;
    #pragma unroll
    for (int kw = 0; kw < 5; ++kw) {
      int ww = w + kw - 2;
      if (ww >= 0 && ww < WW) acc += cw3[hi * 25 + kw * 5 + 2] * zp[ww];
    }
  }
  out[b * WW + w] = acc;
}

extern "C" void kernel_launch(void* const* d_in, const int* in_sizes, int n_in,
                              void* d_out, int out_size, void* d_ws, size_t ws_size,
                              hipStream_t stream) {
  const float* features = (const float*)d_in[0];
  const int*   wbnd     = (const int*)d_in[1];
  const int*   wlen     = (const int*)d_in[2];
  const float* w1  = (const float*)d_in[3];
  const float* b1  = (const float*)d_in[4];
  const float* w2  = (const float*)d_in[5];
  const float* b2  = (const float*)d_in[6];
  const float* w3  = (const float*)d_in[7];
  const float* b3  = (const float*)d_in[8];
  const float* cw1 = (const float*)d_in[9];
  const float* cb1 = (const float*)d_in[10];
  const float* cw2 = (const float*)d_in[11];
  const float* cb2 = (const float*)d_in[12];
  const float* lw  = (const float*)d_in[13];
  const float* lb  = (const float*)d_in[14];
  const float* cw3 = (const float*)d_in[15];
  const float* cb3 = (const float*)d_in[16];
  float* out = (float*)d_out;

  char* ws = (char*)d_ws;
  ushort* ft   = (ushort*)(ws + 0);           // 16,777,216 B  [b][t][128]
  ushort* x1t  = (ushort*)(ws + 16777216);
  ushort* x2t  = (ushort*)(ws + 33554432);
  ushort* embt = (ushort*)(ws + 0);           // over ft (dead after layer1)
  ushort* y1t  = (ushort*)(ws + 16777216);    // 67,108,864 B (x1t/x2t dead)
  float*  z    = (float*)(ws + 83886080);     // 1,048,576 B
  ushort* Wb1  = (ushort*)(ws + 84934656);    // 102,400 B
  ushort* Wb2  = (ushort*)(ws + 85037056);    // 163,840 B
  ushort* Wb3  = (ushort*)(ws + 85200896);    // 163,840 B
  ushort* Wc1  = (ushort*)(ws + 85364736);    // 819,200 B
  ushort* Wc2  = (ushort*)(ws + 86183936);    // 819,200 B
  ushort* zp   = (ushort*)(ws + 87003136);    // 4,096 B zero page

  hipMemsetAsync(zp, 0, 4096, stream);

  const int DYN = 2 * 16896 * 2;              // 67,584 B dynamic LDS
  hipFuncSetAttribute((const void*)conv2d1_mfma,
                      hipFuncAttributeMaxDynamicSharedMemorySize, DYN);
  hipFuncSetAttribute((const void*)conv2d2_mfma,
                      hipFuncAttributeMaxDynamicSharedMemorySize, DYN);

  tr_feat<<<1024, 256, 0, stream>>>(features, ft);
  repack1d<5><<<200, 256, 0, stream>>>(w1, Wb1);
  repack1d<8><<<320, 256, 0, stream>>>(w2, Wb2);
  repack1d<8><<<320, 256, 0, stream>>>(w3, Wb3);
  repack2d<<<1600, 256, 0, stream>>>(cw1, Wc1);
  repack2d<<<1600, 256, 0, stream>>>(cw2, Wc2);
  conv1d_mfma<5, 1><<<512, 256, 0, stream>>>(ft, Wb1, b1, x1t, zp);
  conv1d_mfma<8, 1><<<512, 256, 0, stream>>>(x1t, Wb2, b2, x2t, zp);
  conv1d_mfma<8, 0><<<512, 256, 0, stream>>>(x2t, Wb3, b3, embt, zp);
  conv2d1_mfma<<<BB * WW, 256, DYN, stream>>>(embt, wbnd, wlen, Wc1, cb1, y1t, zp);
  conv2d2_mfma<<<BB * WW, 256, DYN, stream>>>(y1t, Wc2, cb2, lw, lb, z, zp);
  final_k<<<BB, 64, 0, stream>>>(z, cw3, cb3, out);
}